// Round 1
// baseline (239.585 us; speedup 1.0000x reference)
//
#include <hip/hip_runtime.h>
#include <hip/hip_bf16.h>

#define HIDDEN 256
#define NB 4            // batches
#define NQ 200          // queries
#define MT 13           // m-tiles of 16 (208 padded rows)
#define HW 65536        // 256*256 pixels
#define KSTEPS 8        // 256 / 32

typedef __attribute__((ext_vector_type(8))) __bf16 bf16x8;
typedef __attribute__((ext_vector_type(4))) float f32x4;

// ---------------------------------------------------------------------------
// Kernel 1: mask_embed = (relu(q @ w1^T + b1)) @ w2^T + b2, f32 precision.
// Writes result as bf16 in MFMA 16x16x32 A-fragment order into d_ws.
// A_ws layout: [b][mt][ks][lane(64)][j(8)] bf16,
//   element (row = mt*16 + (lane&15), k = ks*32 + (lane>>4)*8 + j)
// Rows >= 200 are zeroed (padding).
// grid: NB*MT blocks, 1024 threads. thread = (rq = tid>>8 owns 4 rows, t = tid&255 owns one d/c)
// ---------------------------------------------------------------------------
__global__ __launch_bounds__(1024)
void mlp_pack(const float* __restrict__ queries,
              const float* __restrict__ w1, const float* __restrict__ b1,
              const float* __restrict__ w2, const float* __restrict__ b2,
              __bf16* __restrict__ A_ws)
{
    __shared__ float qs[16][HIDDEN];
    __shared__ float hs[16][HIDDEN];
    const int blk = blockIdx.x;
    const int b = blk / MT, mt = blk % MT;
    const int tid = threadIdx.x;

    // stage 16 query rows (zero the padded ones)
    for (int idx = tid; idx < 16 * HIDDEN; idx += 1024) {
        int r = idx >> 8, c = idx & 255;
        int q = mt * 16 + r;
        qs[r][c] = (q < NQ) ? queries[((size_t)b * NQ + q) * HIDDEN + c] : 0.f;
    }
    __syncthreads();

    const int t  = tid & 255;   // output-channel index (d for layer1, c for layer2)
    const int rq = tid >> 8;    // row group: rows rq*4 .. rq*4+3

    // layer 1: h[row][t] = relu(b1[t] + sum_c qs[row][c] * w1[t][c])
    float h[4];
    #pragma unroll
    for (int r = 0; r < 4; ++r) h[r] = b1[t];
    for (int c = 0; c < HIDDEN; ++c) {
        float w = w1[(size_t)t * HIDDEN + c];
        #pragma unroll
        for (int r = 0; r < 4; ++r) h[r] = fmaf(qs[rq * 4 + r][c], w, h[r]);
    }
    #pragma unroll
    for (int r = 0; r < 4; ++r) hs[rq * 4 + r][t] = fmaxf(h[r], 0.f);
    __syncthreads();

    // layer 2: me[row][t] = b2[t] + sum_d hs[row][d] * w2[t][d]
    float me[4];
    #pragma unroll
    for (int r = 0; r < 4; ++r) me[r] = b2[t];
    for (int d = 0; d < HIDDEN; ++d) {
        float w = w2[(size_t)t * HIDDEN + d];
        #pragma unroll
        for (int r = 0; r < 4; ++r) me[r] = fmaf(hs[rq * 4 + r][d], w, me[r]);
    }

    // pack to fragment layout (c = t): ks = c>>5, k-group g = (c>>3)&3, j = c&7
    const int ks = t >> 5, g = (t >> 3) & 3, j = t & 7;
    #pragma unroll
    for (int r = 0; r < 4; ++r) {
        int row = rq * 4 + r;            // 0..15 within m-tile
        int q = mt * 16 + row;
        float v = (q < NQ) ? me[r] : 0.f;
        int lane = row + 16 * g;
        size_t addr = ((size_t)((b * MT + mt) * KSTEPS + ks)) * 512 + (size_t)lane * 8 + j;
        A_ws[addr] = (__bf16)v;
    }
}

// ---------------------------------------------------------------------------
// Kernel 2: pred[b][q][n] = sum_c me[b][q][c] * mf[b][c][n]
// One block = one batch x one 64-pixel tile x all 208 (padded) query rows.
// 4 waves; wave w owns pixels [nt*64 + w*16, +16). No LDS, no barriers.
// B-fragment built from 8 per-lane dword loads of mf (f32) -> bf16 in regs.
// grid: NB * (HW/64) = 4096 blocks, 256 threads.
// ---------------------------------------------------------------------------
__global__ __launch_bounds__(256)
void mask_gemm(const float* __restrict__ mf,
               const __bf16* __restrict__ A_ws,
               float* __restrict__ out)
{
    const int bid = blockIdx.x;
    const int b  = bid >> 10;          // HW/64 = 1024 tiles per batch
    const int nt = bid & 1023;
    const int tid  = threadIdx.x;
    const int lane = tid & 63, wv = tid >> 6;
    const int n  = nt * 64 + wv * 16 + (lane & 15);   // this lane's output column
    const int kg = (lane >> 4) * 8;                    // k-group base within k-step

    const float*  mfb = mf   + (size_t)b * HIDDEN * HW;
    const __bf16* Ab  = A_ws + (size_t)b * MT * KSTEPS * 512;

    f32x4 acc[MT];
    #pragma unroll
    for (int mt = 0; mt < MT; ++mt) acc[mt] = (f32x4){0.f, 0.f, 0.f, 0.f};

    #pragma unroll 2
    for (int ks = 0; ks < KSTEPS; ++ks) {
        // --- B fragment: mf[b][ks*32 + kg + j][n], j = 0..7 ---
        const float* src = mfb + (size_t)(ks * 32 + kg) * HW + n;
        float bv[8];
        #pragma unroll
        for (int j = 0; j < 8; ++j) bv[j] = src[(size_t)j * HW];
        bf16x8 bfrag;
        #pragma unroll
        for (int j = 0; j < 8; ++j) bfrag[j] = (__bf16)bv[j];

        // --- A fragments + MFMA ---
        const __bf16* ab = Ab + (size_t)ks * 512 + (size_t)lane * 8;
        #pragma unroll
        for (int mt = 0; mt < MT; ++mt) {
            bf16x8 afrag = *reinterpret_cast<const bf16x8*>(ab + (size_t)mt * KSTEPS * 512);
            acc[mt] = __builtin_amdgcn_mfma_f32_16x16x32_bf16(afrag, bfrag, acc[mt], 0, 0, 0);
        }
    }

    // --- epilogue: C/D layout col = lane&15, row = (lane>>4)*4 + r ---
    const int rowbase = (lane >> 4) * 4;
    float* outb = out + (size_t)b * NQ * HW + n;
    #pragma unroll
    for (int mt = 0; mt < MT; ++mt) {
        #pragma unroll
        for (int r = 0; r < 4; ++r) {
            int q = mt * 16 + rowbase + r;
            if (q < NQ) outb[(size_t)q * HW] = acc[mt][r];
        }
    }
}

// ---------------------------------------------------------------------------
extern "C" void kernel_launch(void* const* d_in, const int* in_sizes, int n_in,
                              void* d_out, int out_size, void* d_ws, size_t ws_size,
                              hipStream_t stream)
{
    const float* queries = (const float*)d_in[0];
    const float* mf      = (const float*)d_in[1];
    const float* w1      = (const float*)d_in[2];
    const float* b1      = (const float*)d_in[3];
    const float* w2      = (const float*)d_in[4];
    const float* b2      = (const float*)d_in[5];
    float*  out  = (float*)d_out;
    __bf16* A_ws = (__bf16*)d_ws;   // needs 4*13*8*512*2 = 425,984 B

    hipLaunchKernelGGL(mlp_pack, dim3(NB * MT), dim3(1024), 0, stream,
                       queries, w1, b1, w2, b2, A_ws);
    hipLaunchKernelGGL(mask_gemm, dim3(NB * (HW / 64)), dim3(256), 0, stream,
                       mf, A_ws, out);
}

// Round 2
// 187.641 us; speedup vs baseline: 1.2768x; 1.2768x over previous
//
#include <hip/hip_runtime.h>
#include <hip/hip_bf16.h>

#define HIDDEN 256
#define NB 4            // batches
#define NQ 200          // queries
#define MT 13           // m-tiles of 16 (208 padded rows)
#define HW 65536        // 256*256 pixels
#define KSTEPS 8        // 256 / 32
#define NPB 256         // pixels per gemm block
#define GEMM_THREADS 512

typedef __attribute__((ext_vector_type(8))) __bf16 bf16x8;
typedef __attribute__((ext_vector_type(4))) float f32x4;

// async global->LDS, 16 B per lane; LDS dest = wave-uniform base + lane*16
__device__ __forceinline__ void gload_lds16(const float* g, float* l) {
    __builtin_amdgcn_global_load_lds(
        (const __attribute__((address_space(1))) void*)g,
        (__attribute__((address_space(3))) void*)l, 16, 0, 0);
}

// ---------------------------------------------------------------------------
// Kernel 1: mask_embed = (relu(q @ w1^T + b1)) @ w2^T + b2, f32 precision.
// Writes result as bf16 in MFMA 16x16x32 A-fragment order into d_ws.
// A_ws layout: [b][mt][ks][lane(64)][j(8)] bf16,
//   element (row = mt*16 + (lane&15), k = ks*32 + (lane>>4)*8 + j)
// v2: w1/w2 staged through LDS in 32-col chunks (coalesced float4 loads)
// instead of per-thread 1KB-strided scalar reads.
// ---------------------------------------------------------------------------
__global__ __launch_bounds__(1024)
void mlp_pack(const float* __restrict__ queries,
              const float* __restrict__ w1, const float* __restrict__ b1,
              const float* __restrict__ w2, const float* __restrict__ b2,
              __bf16* __restrict__ A_ws)
{
    __shared__ float qh[16][HIDDEN];   // query rows, reused for hidden after L1
    __shared__ float wb[HIDDEN][33];   // 256 rows x 32-col chunk, pad -> 2-way banks
    const int blk = blockIdx.x;
    const int b = blk / MT, mt = blk % MT;
    const int tid = threadIdx.x;

    // stage 16 query rows (zero the padded ones)
    for (int idx = tid; idx < 16 * HIDDEN; idx += 1024) {
        int r = idx >> 8, c = idx & 255;
        int q = mt * 16 + r;
        qh[r][c] = (q < NQ) ? queries[((size_t)b * NQ + q) * HIDDEN + c] : 0.f;
    }
    __syncthreads();

    const int t  = tid & 255;   // output-channel index
    const int rq = tid >> 8;    // row group: rows rq*4 .. rq*4+3
    const int sr = tid >> 2;    // staging: weight row
    const int si = tid & 3;     // staging: which float4

    // layer 1
    float h[4];
    #pragma unroll
    for (int r = 0; r < 4; ++r) h[r] = b1[t];
    for (int cc = 0; cc < 8; ++cc) {
        const float* src = w1 + (size_t)sr * HIDDEN + cc * 32;
        float4 va = *reinterpret_cast<const float4*>(src + si * 4);
        float4 vb = *reinterpret_cast<const float4*>(src + 16 + si * 4);
        wb[sr][si*4+0] = va.x; wb[sr][si*4+1] = va.y;
        wb[sr][si*4+2] = va.z; wb[sr][si*4+3] = va.w;
        wb[sr][16+si*4+0] = vb.x; wb[sr][16+si*4+1] = vb.y;
        wb[sr][16+si*4+2] = vb.z; wb[sr][16+si*4+3] = vb.w;
        __syncthreads();
        #pragma unroll
        for (int cl = 0; cl < 32; ++cl) {
            float w = wb[t][cl];
            #pragma unroll
            for (int r = 0; r < 4; ++r)
                h[r] = fmaf(qh[rq * 4 + r][cc * 32 + cl], w, h[r]);
        }
        __syncthreads();
    }

    // relu -> overwrite qh with hidden
    #pragma unroll
    for (int r = 0; r < 4; ++r) qh[rq * 4 + r][t] = fmaxf(h[r], 0.f);
    __syncthreads();

    // layer 2
    float me[4];
    #pragma unroll
    for (int r = 0; r < 4; ++r) me[r] = b2[t];
    for (int cc = 0; cc < 8; ++cc) {
        const float* src = w2 + (size_t)sr * HIDDEN + cc * 32;
        float4 va = *reinterpret_cast<const float4*>(src + si * 4);
        float4 vb = *reinterpret_cast<const float4*>(src + 16 + si * 4);
        wb[sr][si*4+0] = va.x; wb[sr][si*4+1] = va.y;
        wb[sr][si*4+2] = va.z; wb[sr][si*4+3] = va.w;
        wb[sr][16+si*4+0] = vb.x; wb[sr][16+si*4+1] = vb.y;
        wb[sr][16+si*4+2] = vb.z; wb[sr][16+si*4+3] = vb.w;
        __syncthreads();
        #pragma unroll
        for (int cl = 0; cl < 32; ++cl) {
            float w = wb[t][cl];
            #pragma unroll
            for (int r = 0; r < 4; ++r)
                me[r] = fmaf(qh[rq * 4 + r][cc * 32 + cl], w, me[r]);
        }
        __syncthreads();
    }

    // pack to A-fragment layout (c = t): ks = c>>5, k-group g = (c>>3)&3, j = c&7
    const int ks = t >> 5, g = (t >> 3) & 3, j = t & 7;
    #pragma unroll
    for (int r = 0; r < 4; ++r) {
        int row = rq * 4 + r;            // 0..15 within m-tile
        int q = mt * 16 + row;
        float v = (q < NQ) ? me[r] : 0.f;
        int lane = row + 16 * g;
        size_t addr = ((size_t)((b * MT + mt) * KSTEPS + ks)) * 512 + (size_t)lane * 8 + j;
        A_ws[addr] = (__bf16)v;
    }
}

// ---------------------------------------------------------------------------
// Kernel 2: pred[b][q][n] = sum_c me[b][q][c] * mf[b][c][n]
// Block = one batch x 256-pixel tile x all 208 padded q. 512 threads, 8 waves.
// Wave wv owns 32 pixels (2 n-frags) x 13 mt; acc = 13x2 f32x4 = 104 VGPR.
// B-tile (32k x 256n f32) staged to LDS via global_load_lds (1 KB/instr,
// contiguous), double-buffered. Epilogue transposes acc through LDS so each
// output row store is 1 KB contiguous.
// grid: NB * (HW/256) = 1024 blocks.
// ---------------------------------------------------------------------------
__global__ __launch_bounds__(GEMM_THREADS, 2)
void mask_gemm(const float* __restrict__ mf,
               const __bf16* __restrict__ A_ws,
               float* __restrict__ out)
{
    __shared__ float Bst[2][32][NPB];   // 64 KB double-buffered B tile

    const int bid  = blockIdx.x;
    const int b    = bid >> 8;          // 256 tiles per batch
    const int tile = bid & 255;
    const int n0   = tile << 8;
    const int tid  = threadIdx.x;
    const int ln   = tid & 63, wv = tid >> 6;
    const int l15  = ln & 15, lg = ln >> 4;
    const int kg   = lg << 3;           // B-frag k-group base

    const float*  mfb = mf + (size_t)b * HIDDEN * HW + n0;
    const __bf16* Ab  = A_ws + (size_t)b * (MT * KSTEPS * 512);

    f32x4 acc[MT][2];
    #pragma unroll
    for (int m = 0; m < MT; ++m) {
        acc[m][0] = (f32x4){0.f, 0.f, 0.f, 0.f};
        acc[m][1] = (f32x4){0.f, 0.f, 0.f, 0.f};
    }

    // prologue: stage ks=0 into buffer 0 (wave wv stages rows wv*4..wv*4+3)
    {
        const float* g = mfb + (size_t)(wv * 4) * HW + ln * 4;
        #pragma unroll
        for (int i = 0; i < 4; ++i)
            gload_lds16(g + (size_t)i * HW, &Bst[0][wv * 4 + i][0]);
    }
    __syncthreads();

    for (int ks = 0; ks < KSTEPS; ++ks) {
        const int cur = ks & 1;
        // issue next tile's staging loads (async, drains at the barrier)
        if (ks + 1 < KSTEPS) {
            const float* g = mfb + (size_t)((ks + 1) * 32 + wv * 4) * HW + ln * 4;
            #pragma unroll
            for (int i = 0; i < 4; ++i)
                gload_lds16(g + (size_t)i * HW, &Bst[cur ^ 1][wv * 4 + i][0]);
        }
        // B fragments from LDS
        bf16x8 bfr[2];
        #pragma unroll
        for (int f = 0; f < 2; ++f) {
            #pragma unroll
            for (int j = 0; j < 8; ++j)
                bfr[f][j] = (__bf16)Bst[cur][kg + j][wv * 32 + f * 16 + l15];
        }
        // A fragments (L2-resident, 16 B each) + MFMA
        const __bf16* ab = Ab + (size_t)ks * 512 + (size_t)ln * 8;
        #pragma unroll
        for (int m = 0; m < MT; ++m) {
            bf16x8 af = *reinterpret_cast<const bf16x8*>(ab + (size_t)m * (KSTEPS * 512));
            acc[m][0] = __builtin_amdgcn_mfma_f32_16x16x32_bf16(af, bfr[0], acc[m][0], 0, 0, 0);
            acc[m][1] = __builtin_amdgcn_mfma_f32_16x16x32_bf16(af, bfr[1], acc[m][1], 0, 0, 0);
        }
        __syncthreads();
    }

    // epilogue: transpose 2 m-tiles at a time through LDS, 1 KB row stores
    float* Ob = &Bst[0][0][0];                       // 32 x 256 f32 chunk
    float* outb = out + (size_t)b * NQ * HW + n0;
    #pragma unroll
    for (int p = 0; p < 7; ++p) {
        const int mtb = p * 2;
        const int nmt = (p == 6) ? 1 : 2;
        __syncthreads();                             // prior pass done reading Ob
        #pragma unroll
        for (int m = 0; m < 2; ++m) {
            if (m < nmt) {
                #pragma unroll
                for (int f = 0; f < 2; ++f)
                    #pragma unroll
                    for (int r = 0; r < 4; ++r)
                        Ob[(m * 16 + lg * 4 + r) * NPB + wv * 32 + f * 16 + l15] =
                            acc[mtb + m][f][r];
            }
        }
        __syncthreads();
        const int nf4 = nmt * 16 * 64;               // float4s in this chunk
        for (int i = tid; i < nf4; i += GEMM_THREADS) {
            const int row = i >> 6, c4 = (i & 63) << 2;
            const int q = mtb * 16 + row;
            if (q < NQ)
                *reinterpret_cast<float4*>(outb + (size_t)q * HW + c4) =
                    *reinterpret_cast<const float4*>(Ob + row * NPB + c4);
        }
    }
}

// ---------------------------------------------------------------------------
extern "C" void kernel_launch(void* const* d_in, const int* in_sizes, int n_in,
                              void* d_out, int out_size, void* d_ws, size_t ws_size,
                              hipStream_t stream)
{
    const float* queries = (const float*)d_in[0];
    const float* mf      = (const float*)d_in[1];
    const float* w1      = (const float*)d_in[2];
    const float* b1      = (const float*)d_in[3];
    const float* w2      = (const float*)d_in[4];
    const float* b2      = (const float*)d_in[5];
    float*  out  = (float*)d_out;
    __bf16* A_ws = (__bf16*)d_ws;   // 4*13*8*512*2 = 425,984 B

    hipLaunchKernelGGL(mlp_pack, dim3(NB * MT), dim3(1024), 0, stream,
                       queries, w1, b1, w2, b2, A_ws);
    hipLaunchKernelGGL(mask_gemm, dim3(NB * (HW / NPB)), dim3(GEMM_THREADS), 0, stream,
                       mf, A_ws, out);
}